// Round 2
// baseline (2106.520 us; speedup 1.0000x reference)
//
#include <hip/hip_runtime.h>
#include <math.h>

#define N_SAMPLES 131072
#define NDIM 512
#define NCOMP 256
#define NCLASS 8
#define NBIN 100
#define ROWS 32
#define DS_STRIDE 264   // shorts; 528B row stride = 33*16B -> 16B-aligned, bank-spread

typedef float f32x4 __attribute__((ext_vector_type(4)));
typedef short bf16x8 __attribute__((ext_vector_type(8)));

__device__ __forceinline__ unsigned fbits(float x) {
  union { float f; unsigned u; } v; v.f = x; return v.u;
}
__device__ __forceinline__ float bitsf(unsigned u) {
  union { float f; unsigned u; } v; v.u = u; return v.f;
}
__device__ __forceinline__ unsigned short bf16_rne(float x) {
  unsigned u = fbits(x);
  unsigned r = u + 0x7fffu + ((u >> 16) & 1u);
  return (unsigned short)(r >> 16);
}

// ---- pre-pass: convert wT once into bf16 tables in workspace ----
// ws layout (shorts): whiT[c][k] (transposed hi), wloT[c][k] (transposed lo),
//                     wbh[m][c]  (native rne bf16, for phase 3)
__global__ void prep_w(const float* __restrict__ wT, unsigned short* __restrict__ ws) {
  const int id = blockIdx.x * blockDim.x + threadIdx.x;  // 0..NDIM*NCOMP-1
  const int m = id >> 8;       // 0..511  (wT row / dim index)
  const int c = id & 255;      // 0..255  (component)
  const float v = wT[(size_t)m * NCOMP + c];
  const unsigned u = fbits(v);
  const unsigned short hi = (unsigned short)(u >> 16);
  const float hf = bitsf(u & 0xffff0000u);
  const unsigned short lo = bf16_rne(v - hf);
  unsigned short* whiT = ws;
  unsigned short* wloT = ws + (size_t)NCOMP * NDIM;
  unsigned short* wbh  = ws + (size_t)2 * NCOMP * NDIM;
  whiT[(size_t)c * NDIM + m] = hi;
  wloT[(size_t)c * NDIM + m] = lo;
  wbh [(size_t)m * NCOMP + c] = bf16_rne(v);
}

// Fused kernel, one block = 32 rows, 4 waves (256 threads).
// Phase 1: data0 = data @ wT via split-bf16 MFMA (AhBh + AlBh + AhBl ~ fp32).
//          A frags from global data; B frags from precomputed bf16 tables (USE_WS)
//          or gathered+converted from fp32 wT (fallback). No LDS, no barriers.
// Phase 2: RQ spline fully in-register on the MFMA accumulators; branchless
//          8-wide-interleaved lower_bound; delta -> bf16 LDS tile; logj via
//          shfl reduce. One __syncthreads total.
// Phase 3: out^T = wT * delta^T (wT A-frags native-layout bf16, delta from LDS
//          as contiguous b128); epilogue adds data, stores float4.
template <bool USE_WS>
__global__ __launch_bounds__(256, 4) void cst_mfma(
    const float* __restrict__ data,
    const float* __restrict__ wT,
    const float* __restrict__ kx,
    const float* __restrict__ ky,
    const float* __restrict__ kd,
    const int*   __restrict__ label,
    const unsigned short* __restrict__ ws,
    float* __restrict__ out,
    float* __restrict__ logj)
{
  __shared__ __align__(16) unsigned short dS[ROWS * DS_STRIDE]; // delta, bf16
  __shared__ float ljS[ROWS][2];

  const int t    = threadIdx.x;
  const int lane = t & 63;
  const int wv   = t >> 6;        // wave 0..3
  const int l15  = lane & 15;
  const int g    = lane >> 4;     // 0..3
  const int rowBase = blockIdx.x * ROWS;

  const int Rw = (wv & 1) * 16;   // phase-1 row block of this wave
  const int Cw = (wv >> 1) * 128; // phase-1 comp block of this wave

  const unsigned short* whiT = ws;
  const unsigned short* wloT = ws + (size_t)NCOMP * NDIM;
  const unsigned short* wbh  = ws + (size_t)2 * NCOMP * NDIM;

  // ================= Phase 1: data0 = data @ wT (3-product split bf16) ====
  const f32x4 zf = {0.f, 0.f, 0.f, 0.f};
  f32x4 acc[8];
#pragma unroll
  for (int f = 0; f < 8; ++f) acc[f] = zf;

  const float* aptr  = data + (size_t)(rowBase + Rw + l15) * NDIM + 8 * g;
  const float* bbase = wT + (size_t)(8 * g) * NCOMP + Cw + l15;

#pragma unroll 2
  for (int d0 = 0; d0 < NDIM; d0 += 32) {
    const float4 a0 = *(const float4*)(aptr + d0);
    const float4 a1 = *(const float4*)(aptr + d0 + 4);
    const float av[8] = {a0.x, a0.y, a0.z, a0.w, a1.x, a1.y, a1.z, a1.w};
    bf16x8 ah, al;
#pragma unroll
    for (int j = 0; j < 8; ++j) {
      const unsigned u = fbits(av[j]);
      const float hf = bitsf(u & 0xffff0000u);  // truncation-split; lo repairs it
      ah[j] = (short)(u >> 16);
      al[j] = (short)bf16_rne(av[j] - hf);
    }
#pragma unroll
    for (int f = 0; f < 8; ++f) {
      bf16x8 bh, bl;
      if constexpr (USE_WS) {
        const size_t boff = (size_t)(Cw + 16 * f + l15) * NDIM + d0 + 8 * g;
        bh = *(const bf16x8*)&whiT[boff];
        bl = *(const bf16x8*)&wloT[boff];
      } else {
        const float* bp = bbase + (size_t)d0 * NCOMP + 16 * f;
        float bv[8];
#pragma unroll
        for (int j = 0; j < 8; ++j) bv[j] = bp[(size_t)j * NCOMP];
#pragma unroll
        for (int j = 0; j < 8; ++j) {
          const unsigned u = fbits(bv[j]);
          const float hf = bitsf(u & 0xffff0000u);
          bh[j] = (short)(u >> 16);
          bl[j] = (short)bf16_rne(bv[j] - hf);
        }
      }
      acc[f] = __builtin_amdgcn_mfma_f32_16x16x32_bf16(ah, bh, acc[f], 0, 0, 0);
      acc[f] = __builtin_amdgcn_mfma_f32_16x16x32_bf16(al, bh, acc[f], 0, 0, 0);
      acc[f] = __builtin_amdgcn_mfma_f32_16x16x32_bf16(ah, bl, acc[f], 0, 0, 0);
    }
  }
  // acc[f][r] = data0[row = Rw + 4g + r][c = Cw + 16f + l15]

  // ================= Phase 2: RQ spline in-register, logj, delta -> LDS ====
  int labs[4];
#pragma unroll
  for (int r = 0; r < 4; ++r) labs[r] = label[rowBase + Rw + 4 * g + r];

#pragma unroll
  for (int r = 0; r < 4; ++r) {
    const size_t tb = (size_t)labs[r] * (NCOMP * NBIN) + (size_t)(Cw + l15) * NBIN;
    const float* xkp = kx + tb;
    const float* ykp = ky + tb;
    const float* dkp = kd + tb;
    float xv[8];
    int   idx[8];
#pragma unroll
    for (int f = 0; f < 8; ++f) xv[f] = acc[f][r];
    // branchless lower_bound over 100 knots, 8 independent searches in lockstep
#pragma unroll
    for (int f = 0; f < 8; ++f)
      idx[f] = (xkp[f * (16 * NBIN) + 63] < xv[f]) ? 36 : 0;
#pragma unroll
    for (int s = 32; s >= 1; s >>= 1) {
#pragma unroll
      for (int f = 0; f < 8; ++f)
        idx[f] += (xkp[f * (16 * NBIN) + idx[f] + s - 1] < xv[f]) ? s : 0;
    }
#pragma unroll
    for (int f = 0; f < 8; ++f)
      idx[f] += (xkp[f * (16 * NBIN) + idx[f]] < xv[f]) ? 1 : 0;

    const int row = Rw + 4 * g + r;
    float lsum = 0.f;
#pragma unroll
    for (int f = 0; f < 8; ++f) {
      const float x = xv[f];
      const int lo  = idx[f];
      int k = lo - 1; k = k < 0 ? 0 : k; k = k > (NBIN - 2) ? (NBIN - 2) : k;
      const float* xk8 = xkp + f * (16 * NBIN);
      const float* yk8 = ykp + f * (16 * NBIN);
      const float* dk8 = dkp + f * (16 * NBIN);
      const float x0 = xk8[k],  x1 = xk8[k + 1];
      const float y0 = yk8[k],  y1 = yk8[k + 1];
      const float dd0 = dk8[k], dd1 = dk8[k + 1];
      const float wdt = x1 - x0;
      const float sl  = (y1 - y0) / wdt;
      float xi = (x - x0) / wdt;
      xi = fminf(fmaxf(xi, 0.f), 1.f);
      const float xi1 = 1.f - xi;
      const float den = sl + (dd0 + dd1 - 2.f * sl) * xi * xi1;
      const float num = sl * xi * xi + dd0 * xi * xi1;
      const float y_in = y0 + (y1 - y0) * num / den;
      const float ldn  = dd1 * xi * xi + 2.f * sl * xi * xi1 + dd0 * xi1 * xi1;
      const bool below = (lo == 0), above = (lo == NBIN);
      const bool edge  = below || above;
      const float xe = below ? x0 : x1;     // k clamped: x0=xk[0] / x1=xk[99]
      const float ye = below ? y0 : y1;
      const float de = below ? dd0 : dd1;
      const float y_e = ye + de * (x - xe); // linear extrapolation
      const float Aa = edge ? de  : ldn;    // predicated log args (log(1)=0)
      const float Ab = edge ? 1.f : sl;
      const float Ac = edge ? 1.f : den;
      const float y  = edge ? y_e : y_in;
      lsum += logf(Aa) + 2.f * logf(Ab) - 2.f * logf(Ac);
      const int c = Cw + 16 * f + l15;
      dS[row * DS_STRIDE + c] = bf16_rne(y - x);
    }
    float v = lsum;
    v += __shfl_xor(v, 1, 16);
    v += __shfl_xor(v, 2, 16);
    v += __shfl_xor(v, 4, 16);
    v += __shfl_xor(v, 8, 16);
    if (l15 == 0) ljS[row][wv >> 1] = v;
  }
  __syncthreads();
  if (t < ROWS) logj[rowBase + t] = ljS[t][0] + ljS[t][1];

  // ======= Phase 3: out = data + delta @ wT^T, computed as out^T = wT*delta^T
  f32x4 a3[8][2];
#pragma unroll
  for (int fm = 0; fm < 8; ++fm) { a3[fm][0] = zf; a3[fm][1] = zf; }

  const int m00 = wv * 128;  // this wave's 128 output columns
  const float* wp3 = wT + (size_t)(m00 + l15) * NCOMP + 8 * g;

#pragma unroll 2
  for (int c0 = 0; c0 < NCOMP; c0 += 32) {
    const bf16x8 b0 = *(const bf16x8*)&dS[l15 * DS_STRIDE + c0 + 8 * g];
    const bf16x8 b1 = *(const bf16x8*)&dS[(16 + l15) * DS_STRIDE + c0 + 8 * g];
#pragma unroll
    for (int fm = 0; fm < 8; ++fm) {
      bf16x8 af;
      if constexpr (USE_WS) {
        af = *(const bf16x8*)&wbh[(size_t)(m00 + fm * 16 + l15) * NCOMP + c0 + 8 * g];
      } else {
        const float* ap = wp3 + (size_t)(fm * 16) * NCOMP + c0;
        const float4 q0 = *(const float4*)ap;
        const float4 q1 = *(const float4*)(ap + 4);
        const float qv[8] = {q0.x, q0.y, q0.z, q0.w, q1.x, q1.y, q1.z, q1.w};
#pragma unroll
        for (int j = 0; j < 8; ++j) af[j] = (short)bf16_rne(qv[j]);
      }
      a3[fm][0] = __builtin_amdgcn_mfma_f32_16x16x32_bf16(af, b0, a3[fm][0], 0, 0, 0);
      a3[fm][1] = __builtin_amdgcn_mfma_f32_16x16x32_bf16(af, b1, a3[fm][1], 0, 0, 0);
    }
  }

  // epilogue: out[row][col..col+3] = data + acc ; D-frag: col-in-frag=l15(row),
  // row-in-frag = 4g + reg (consecutive out columns -> float4)
#pragma unroll
  for (int fm = 0; fm < 8; ++fm) {
#pragma unroll
    for (int fn = 0; fn < 2; ++fn) {
      const int row = rowBase + fn * 16 + l15;
      const int col = m00 + fm * 16 + 4 * g;
      const size_t base = (size_t)row * NDIM + col;
      const float4 dv = *(const float4*)(data + base);
      float4 o;
      o.x = dv.x + a3[fm][fn][0];
      o.y = dv.y + a3[fm][fn][1];
      o.z = dv.z + a3[fm][fn][2];
      o.w = dv.w + a3[fm][fn][3];
      *(float4*)(out + base) = o;
    }
  }
}

extern "C" void kernel_launch(void* const* d_in, const int* in_sizes, int n_in,
                              void* d_out, int out_size, void* d_ws, size_t ws_size,
                              hipStream_t stream) {
  const float* data = (const float*)d_in[0];
  const float* wT   = (const float*)d_in[1];
  const float* kx   = (const float*)d_in[2];
  const float* ky   = (const float*)d_in[3];
  const float* kd   = (const float*)d_in[4];
  const int*   lab  = (const int*)d_in[5];
  float* outp = (float*)d_out;
  float* lj   = outp + (size_t)N_SAMPLES * NDIM;   // outputs concatenated: out, logj

  const size_t ws_need = (size_t)3 * NCOMP * NDIM * sizeof(unsigned short); // 768 KB
  dim3 grid(N_SAMPLES / ROWS);
  if (d_ws != nullptr && ws_size >= ws_need) {
    unsigned short* wsp = (unsigned short*)d_ws;
    prep_w<<<dim3((NDIM * NCOMP) / 256), 256, 0, stream>>>(wT, wsp);
    cst_mfma<true><<<grid, 256, 0, stream>>>(data, wT, kx, ky, kd, lab, wsp, outp, lj);
  } else {
    cst_mfma<false><<<grid, 256, 0, stream>>>(data, wT, kx, ky, kd, lab, nullptr, outp, lj);
  }
}

// Round 3
// 1143.273 us; speedup vs baseline: 1.8425x; 1.8425x over previous
//
#include <hip/hip_runtime.h>
#include <math.h>

#define N_SAMPLES 131072
#define NDIM 512
#define NCOMP 256
#define NCLASS 8
#define NBIN 100
#define ROWS 32
#define DS_STRIDE 264   // shorts; 528B row stride = 33*16B -> 16B-aligned, bank-spread

typedef float f32x4 __attribute__((ext_vector_type(4)));
typedef short bf16x8 __attribute__((ext_vector_type(8)));

__device__ __forceinline__ unsigned fbits(float x) {
  union { float f; unsigned u; } v; v.f = x; return v.u;
}
__device__ __forceinline__ float bitsf(unsigned u) {
  union { float f; unsigned u; } v; v.u = u; return v.f;
}
__device__ __forceinline__ unsigned short bf16_rne(float x) {
  unsigned u = fbits(x);
  unsigned r = u + 0x7fffu + ((u >> 16) & 1u);
  return (unsigned short)(r >> 16);
}

// ---- ws layout (bytes) ----
// [0,        262144)  whiT2  shorts, blocked [k/8][c][k%8]   (phase-1 B hi)
// [262144,   524288)  wloT2  shorts, blocked [k/8][c][k%8]   (phase-1 B lo)
// [524288,   786432)  wbh2   shorts, blocked [c/8][m][c%8]   (phase-3 A)
// [786432,   802816)  soff   float2[NCLASS*NCOMP] = (scale, xk0)
// [802816,  2441216)  ydk    float2[NCLASS*NCOMP*NBIN] = (y_k, d_k)
#define WS_BYTES 2441216

__global__ void prep_w(const float* __restrict__ wT, const float* __restrict__ kx,
                       const float* __restrict__ ky, const float* __restrict__ kd,
                       unsigned short* __restrict__ wsS,
                       float2* __restrict__ soff, float2* __restrict__ ydk) {
  const int id = blockIdx.x * blockDim.x + threadIdx.x;   // 0 .. 204799
  if (id < NDIM * NCOMP) {
    const int m = id >> 8;       // 0..511 (dim / k index)
    const int c = id & 255;      // 0..255 (component)
    const float v = wT[(size_t)m * NCOMP + c];
    const unsigned u = fbits(v);
    const unsigned short hi = (unsigned short)(u >> 16);
    const float hf = bitsf(u & 0xffff0000u);
    const unsigned short lo = bf16_rne(v - hf);
    unsigned short* whiT2 = wsS;
    unsigned short* wloT2 = wsS + 131072;
    unsigned short* wbh2  = wsS + 262144;
    const int wi = ((m >> 3) * NCOMP + c) * 8 + (m & 7);
    whiT2[wi] = hi;
    wloT2[wi] = lo;
    wbh2[((c >> 3) * NDIM + m) * 8 + (c & 7)] = bf16_rne(v);
  }
  if (id < NCLASS * NCOMP * NBIN) {
    ydk[id] = make_float2(ky[id], kd[id]);    // same linear (class,comp,bin) order
  }
  if (id < NCLASS * NCOMP) {
    const size_t b = (size_t)id * NBIN;
    const float x0 = kx[b], x99 = kx[b + NBIN - 1];
    soff[id] = make_float2((float)(NBIN - 1) / (x99 - x0), x0);
  }
}

// Fused kernel, one block = 32 rows, 4 waves (256 threads).
// Phase 1: data0 = data @ wT via split-bf16 MFMA; B frags are dense b128 loads
//          from the blocked bf16 tables (USE_WS) or gathered fp32 (fallback).
// Phase 2: RQ spline in-register. USE_WS: linear-guess + 16-float window search
//          (2-3 dependent load stages) + register count/minmax reduce; rare
//          binary-search fallback. Eval knots from interleaved (y,d) table.
// Phase 3: out^T = wT * delta^T, A frags dense b128 from blocked wbh2.
template <bool USE_WS>
__global__ __launch_bounds__(256, 3) void cst_mfma(
    const float* __restrict__ data,
    const float* __restrict__ wT,
    const float* __restrict__ kx,
    const float* __restrict__ ky,
    const float* __restrict__ kd,
    const int*   __restrict__ label,
    const unsigned short* __restrict__ ws,
    const float2* __restrict__ soff,
    const float2* __restrict__ ydk,
    float* __restrict__ out,
    float* __restrict__ logj)
{
  __shared__ __align__(16) unsigned short dS[ROWS * DS_STRIDE]; // delta, bf16
  __shared__ float ljS[ROWS][2];

  const int t    = threadIdx.x;
  const int lane = t & 63;
  const int wv   = t >> 6;        // wave 0..3
  const int l15  = lane & 15;
  const int g    = lane >> 4;     // 0..3
  const int rowBase = blockIdx.x * ROWS;

  const int Rw = (wv & 1) * 16;   // phase-1 row block of this wave
  const int Cw = (wv >> 1) * 128; // phase-1 comp block of this wave

  const unsigned short* whiT2 = ws;
  const unsigned short* wloT2 = ws + 131072;
  const unsigned short* wbh2  = ws + 262144;

  // hoist labels so the loads fly during phase 1
  int labs[4];
#pragma unroll
  for (int r = 0; r < 4; ++r) labs[r] = label[rowBase + Rw + 4 * g + r];

  // ================= Phase 1: data0 = data @ wT (3-product split bf16) ====
  const f32x4 zf = {0.f, 0.f, 0.f, 0.f};
  f32x4 acc[8];
#pragma unroll
  for (int f = 0; f < 8; ++f) acc[f] = zf;

  const float* aptr  = data + (size_t)(rowBase + Rw + l15) * NDIM + 8 * g;
  const float* bbase = wT + (size_t)(8 * g) * NCOMP + Cw + l15;

#pragma unroll 2
  for (int d0 = 0; d0 < NDIM; d0 += 32) {
    const float4 a0 = *(const float4*)(aptr + d0);
    const float4 a1 = *(const float4*)(aptr + d0 + 4);
    const float av[8] = {a0.x, a0.y, a0.z, a0.w, a1.x, a1.y, a1.z, a1.w};
    bf16x8 ah, al;
#pragma unroll
    for (int j = 0; j < 8; ++j) {
      const unsigned u = fbits(av[j]);
      const float hf = bitsf(u & 0xffff0000u);  // truncation-split; lo repairs it
      ah[j] = (short)(u >> 16);
      al[j] = (short)bf16_rne(av[j] - hf);
    }
#pragma unroll
    for (int f = 0; f < 8; ++f) {
      bf16x8 bh, bl;
      if constexpr (USE_WS) {
        const size_t boff = ((size_t)((d0 >> 3) + g) * NCOMP + (Cw + 16 * f + l15)) * 8;
        bh = *(const bf16x8*)&whiT2[boff];
        bl = *(const bf16x8*)&wloT2[boff];
      } else {
        const float* bp = bbase + (size_t)d0 * NCOMP + 16 * f;
        float bv[8];
#pragma unroll
        for (int j = 0; j < 8; ++j) bv[j] = bp[(size_t)j * NCOMP];
#pragma unroll
        for (int j = 0; j < 8; ++j) {
          const unsigned u = fbits(bv[j]);
          const float hf = bitsf(u & 0xffff0000u);
          bh[j] = (short)(u >> 16);
          bl[j] = (short)bf16_rne(bv[j] - hf);
        }
      }
      acc[f] = __builtin_amdgcn_mfma_f32_16x16x32_bf16(ah, bh, acc[f], 0, 0, 0);
      acc[f] = __builtin_amdgcn_mfma_f32_16x16x32_bf16(al, bh, acc[f], 0, 0, 0);
      acc[f] = __builtin_amdgcn_mfma_f32_16x16x32_bf16(ah, bl, acc[f], 0, 0, 0);
    }
  }
  // acc[f][r] = data0[row = Rw + 4g + r][c = Cw + 16f + l15]

  // ================= Phase 2: RQ spline in-register, logj, delta -> LDS ====
#pragma unroll
  for (int r = 0; r < 4; ++r) {
    const int cbase = labs[r] * NCOMP + Cw + l15;   // linear (class,comp) index
    const int row = Rw + 4 * g + r;
    float lsum = 0.f;
#pragma unroll
    for (int f = 0; f < 8; ++f) {
      const float x = acc[f][r];
      const int cidx = cbase + 16 * f;
      const float* xkf = kx + (size_t)cidx * NBIN;
      int lo;
      float x0, x1, y0v, y1v, dd0, dd1;
      if constexpr (USE_WS) {
        const float2 so = soff[cidx];
        const float gf = (x - so.y) * so.x;          // approx knot index
        int w0 = (int)gf - 6;
        w0 = w0 < 0 ? 0 : (w0 > 84 ? 84 : w0);
        w0 &= ~3;                                    // 16B-aligned window start
        const float4 Wa = *(const float4*)(xkf + w0);
        const float4 Wb = *(const float4*)(xkf + w0 + 4);
        const float4 Wc = *(const float4*)(xkf + w0 + 8);
        const float4 Wd = *(const float4*)(xkf + w0 + 12);
        int cnt = 0; float xlo = -__builtin_inff(), xhi = __builtin_inff();
#define WSTEP(v) { const bool c_ = (v) < x; cnt += c_ ? 1 : 0; \
                   xlo = c_ ? fmaxf(xlo, (v)) : xlo; xhi = c_ ? xhi : fminf(xhi, (v)); }
        WSTEP(Wa.x) WSTEP(Wa.y) WSTEP(Wa.z) WSTEP(Wa.w)
        WSTEP(Wb.x) WSTEP(Wb.y) WSTEP(Wb.z) WSTEP(Wb.w)
        WSTEP(Wc.x) WSTEP(Wc.y) WSTEP(Wc.z) WSTEP(Wc.w)
        WSTEP(Wd.x) WSTEP(Wd.y) WSTEP(Wd.z) WSTEP(Wd.w)
#undef WSTEP
        lo = w0 + cnt;
        const bool ok_lo = (w0 == 0)  || (Wa.x < x);   // true lo-1 >= w0 (or lo==0)
        const bool ok_hi = (w0 == 84) || (Wd.w >= x);  // true lo   <= w0+15 (or ==100)
        if (__builtin_expect(!(ok_lo && ok_hi), 0)) {  // rare: guess missed
          int l2 = 0, h2 = NBIN;
          while (l2 < h2) { const int mid = (l2 + h2) >> 1;
                            if (xkf[mid] < x) l2 = mid + 1; else h2 = mid; }
          lo = l2;
          const int kk = min(max(lo - 1, 0), NBIN - 2);
          x0 = xkf[kk]; x1 = xkf[kk + 1];
        } else {
          x0 = (cnt == 0)  ? Wa.x : xlo;   // largest knot < x  (= xk[lo-1])
          x1 = (cnt == 16) ? Wd.w : xhi;   // smallest knot >= x (= xk[lo])
        }
        const int k = min(max(lo - 1, 0), NBIN - 2);
        const float2 yd0 = ydk[(size_t)cidx * NBIN + k];
        const float2 yd1 = ydk[(size_t)cidx * NBIN + k + 1];
        y0v = yd0.x; dd0 = yd0.y; y1v = yd1.x; dd1 = yd1.y;
      } else {
        const float* ykf = ky + (size_t)cidx * NBIN;
        const float* dkf = kd + (size_t)cidx * NBIN;
        int l2 = 0, h2 = NBIN;
        while (l2 < h2) { const int mid = (l2 + h2) >> 1;
                          if (xkf[mid] < x) l2 = mid + 1; else h2 = mid; }
        lo = l2;
        const int k = min(max(lo - 1, 0), NBIN - 2);
        x0 = xkf[k]; x1 = xkf[k + 1];
        y0v = ykf[k]; y1v = ykf[k + 1];
        dd0 = dkf[k]; dd1 = dkf[k + 1];
      }
      // ---- shared eval (identical arithmetic to the verified round-2 kernel)
      const float wdt = x1 - x0;
      const float sl  = (y1v - y0v) / wdt;
      float xi = (x - x0) / wdt;
      xi = fminf(fmaxf(xi, 0.f), 1.f);
      const float xi1 = 1.f - xi;
      const float den = sl + (dd0 + dd1 - 2.f * sl) * xi * xi1;
      const float num = sl * xi * xi + dd0 * xi * xi1;
      const float y_in = y0v + (y1v - y0v) * num / den;
      const float ldn  = dd1 * xi * xi + 2.f * sl * xi * xi1 + dd0 * xi1 * xi1;
      const bool below = (lo == 0), above = (lo == NBIN);
      const bool edge  = below || above;
      const float xe = below ? x0 : x1;
      const float ye = below ? y0v : y1v;
      const float de = below ? dd0 : dd1;
      const float y_e = ye + de * (x - xe);          // linear extrapolation
      const float Aa = edge ? de  : ldn;             // predicated log args
      const float Ab = edge ? 1.f : sl;
      const float Ac = edge ? 1.f : den;
      const float y  = edge ? y_e : y_in;
      lsum += logf(Aa) + 2.f * logf(Ab) - 2.f * logf(Ac);
      dS[row * DS_STRIDE + Cw + 16 * f + l15] = bf16_rne(y - x);
    }
    float v = lsum;
    v += __shfl_xor(v, 1, 16);
    v += __shfl_xor(v, 2, 16);
    v += __shfl_xor(v, 4, 16);
    v += __shfl_xor(v, 8, 16);
    if (l15 == 0) ljS[row][wv >> 1] = v;
  }
  __syncthreads();
  if (t < ROWS) logj[rowBase + t] = ljS[t][0] + ljS[t][1];

  // ======= Phase 3: out = data + delta @ wT^T, computed as out^T = wT*delta^T
  f32x4 a3[8][2];
#pragma unroll
  for (int fm = 0; fm < 8; ++fm) { a3[fm][0] = zf; a3[fm][1] = zf; }

  const int m00 = wv * 128;  // this wave's 128 output columns
  const float* wp3 = wT + (size_t)(m00 + l15) * NCOMP + 8 * g;

#pragma unroll 2
  for (int c0 = 0; c0 < NCOMP; c0 += 32) {
    const bf16x8 b0 = *(const bf16x8*)&dS[l15 * DS_STRIDE + c0 + 8 * g];
    const bf16x8 b1 = *(const bf16x8*)&dS[(16 + l15) * DS_STRIDE + c0 + 8 * g];
#pragma unroll
    for (int fm = 0; fm < 8; ++fm) {
      bf16x8 af;
      if constexpr (USE_WS) {
        af = *(const bf16x8*)&wbh2[((size_t)((c0 >> 3) + g) * NDIM
                                    + (m00 + fm * 16 + l15)) * 8];
      } else {
        const float* ap = wp3 + (size_t)(fm * 16) * NCOMP + c0;
        const float4 q0 = *(const float4*)ap;
        const float4 q1 = *(const float4*)(ap + 4);
        const float qv[8] = {q0.x, q0.y, q0.z, q0.w, q1.x, q1.y, q1.z, q1.w};
#pragma unroll
        for (int j = 0; j < 8; ++j) af[j] = (short)bf16_rne(qv[j]);
      }
      a3[fm][0] = __builtin_amdgcn_mfma_f32_16x16x32_bf16(af, b0, a3[fm][0], 0, 0, 0);
      a3[fm][1] = __builtin_amdgcn_mfma_f32_16x16x32_bf16(af, b1, a3[fm][1], 0, 0, 0);
    }
  }

  // epilogue: out[row][col..col+3] = data + acc
#pragma unroll
  for (int fm = 0; fm < 8; ++fm) {
#pragma unroll
    for (int fn = 0; fn < 2; ++fn) {
      const int row = rowBase + fn * 16 + l15;
      const int col = m00 + fm * 16 + 4 * g;
      const size_t base = (size_t)row * NDIM + col;
      const float4 dv = *(const float4*)(data + base);
      float4 o;
      o.x = dv.x + a3[fm][fn][0];
      o.y = dv.y + a3[fm][fn][1];
      o.z = dv.z + a3[fm][fn][2];
      o.w = dv.w + a3[fm][fn][3];
      *(float4*)(out + base) = o;
    }
  }
}

extern "C" void kernel_launch(void* const* d_in, const int* in_sizes, int n_in,
                              void* d_out, int out_size, void* d_ws, size_t ws_size,
                              hipStream_t stream) {
  const float* data = (const float*)d_in[0];
  const float* wT   = (const float*)d_in[1];
  const float* kx   = (const float*)d_in[2];
  const float* ky   = (const float*)d_in[3];
  const float* kd   = (const float*)d_in[4];
  const int*   lab  = (const int*)d_in[5];
  float* outp = (float*)d_out;
  float* lj   = outp + (size_t)N_SAMPLES * NDIM;   // outputs concatenated: out, logj

  dim3 grid(N_SAMPLES / ROWS);
  if (d_ws != nullptr && ws_size >= (size_t)WS_BYTES) {
    unsigned short* wsS = (unsigned short*)d_ws;
    float2* soff = (float2*)((char*)d_ws + 786432);
    float2* ydk  = (float2*)((char*)d_ws + 802816);
    prep_w<<<dim3((NCLASS * NCOMP * NBIN) / 256), 256, 0, stream>>>(
        wT, kx, ky, kd, wsS, soff, ydk);
    cst_mfma<true><<<grid, 256, 0, stream>>>(data, wT, kx, ky, kd, lab,
                                             wsS, soff, ydk, outp, lj);
  } else {
    cst_mfma<false><<<grid, 256, 0, stream>>>(data, wT, kx, ky, kd, lab,
                                              nullptr, nullptr, nullptr, outp, lj);
  }
}